// Round 2
// baseline (788.178 us; speedup 1.0000x reference)
//
#include <hip/hip_runtime.h>
#include <hip/hip_bf16.h>

#define TT 200
#define UU 50
#define BB 8
#define DJ 1024   // D_JOINT
#define DE 512    // D_ENC / D_DEC
#define VV 1024
#define M_TOTAL (BB*TT*UU)   // 80000
#define MB 80                // M rows per block
#define NITER 32             // K / 32

typedef __bf16 bf16x8 __attribute__((ext_vector_type(8)));
typedef float f32x4 __attribute__((ext_vector_type(4)));
typedef unsigned short ushort8 __attribute__((ext_vector_type(8)));

__device__ __forceinline__ unsigned short f2bf(float f) {
    union { float f; unsigned u; } v; v.f = f;
    unsigned r = v.u + 0x7FFFu + ((v.u >> 16) & 1u);   // RNE
    return (unsigned short)(r >> 16);
}

__device__ __forceinline__ float fast_tanh(float x) {
    float e = __expf(2.f * x);
    return 1.f - 2.f / (e + 1.f);
}

__device__ __forceinline__ ushort8 tanh_pack(float4 e0, float4 e1, float4 d0, float4 d1) {
    ushort8 h;
    h[0] = f2bf(fast_tanh(e0.x + d0.x)); h[1] = f2bf(fast_tanh(e0.y + d0.y));
    h[2] = f2bf(fast_tanh(e0.z + d0.z)); h[3] = f2bf(fast_tanh(e0.w + d0.w));
    h[4] = f2bf(fast_tanh(e1.x + d1.x)); h[5] = f2bf(fast_tanh(e1.y + d1.y));
    h[6] = f2bf(fast_tanh(e1.z + d1.z)); h[7] = f2bf(fast_tanh(e1.w + d1.w));
    return h;
}

__device__ __forceinline__ void gload_lds16(const unsigned short* g, unsigned short* l) {
    __builtin_amdgcn_global_load_lds(
        (const __attribute__((address_space(1))) unsigned int*)(const void*)g,
        (__attribute__((address_space(3))) unsigned int*)(void*)l, 16, 0, 0);
}

// ---------- kernel 1: W_fc fp32 -> bf16 ----------
__global__ void k_wfc_bf16(const float* __restrict__ w, unsigned short* __restrict__ o) {
    int i = (blockIdx.x * 256 + threadIdx.x) * 8;
    float4 a = *(const float4*)(w + i);
    float4 b = *(const float4*)(w + i + 4);
    ushort8 h;
    h[0] = f2bf(a.x); h[1] = f2bf(a.y); h[2] = f2bf(a.z); h[3] = f2bf(a.w);
    h[4] = f2bf(b.x); h[5] = f2bf(b.y); h[6] = f2bf(b.z); h[7] = f2bf(b.w);
    *(ushort8*)(o + i) = h;
}

// ---------- kernel 2: projection  out[m][j] = sum_d in[m][d]*W[j][d] + b[j] ----------
__global__ __launch_bounds__(256) void k_proj(const float* __restrict__ in,
                                              const float* __restrict__ W,
                                              const float* __restrict__ bias,
                                              float* __restrict__ out) {
    __shared__ float in_s[16][DE];
    const int m0 = blockIdx.x * 16;
    const int tid = threadIdx.x;
    #pragma unroll
    for (int it = 0; it < 8; ++it) {
        int idx = tid + it * 256;
        int r = idx >> 7, c = (idx & 127) << 2;
        *(float4*)&in_s[r][c] = *(const float4*)(in + (size_t)(m0 + r) * DE + c);
    }
    __syncthreads();
    const int j = blockIdx.y * 256 + tid;
    const float4* wr = (const float4*)(W + (size_t)j * DE);
    float acc[16];
    #pragma unroll
    for (int r = 0; r < 16; ++r) acc[r] = 0.f;
    for (int d4 = 0; d4 < DE / 4; ++d4) {
        float4 w = wr[d4];
        #pragma unroll
        for (int r = 0; r < 16; ++r) {
            float4 x = *(const float4*)&in_s[r][d4 << 2];
            acc[r] += x.x * w.x + x.y * w.y + x.z * w.z + x.w * w.w;
        }
    }
    float bv = bias[j];
    #pragma unroll
    for (int r = 0; r < 16; ++r)
        out[(size_t)(m0 + r) * DJ + j] = acc[r] + bv;
}

// ---------- kernel 3: fused tanh(enc+dec) @ W_fc^T + b_fc -> log_softmax ----------
// 512 threads (8 waves). Block tile: 80 M x 1024 N, K double-buffered in 32-chunks.
// B chunk in LDS as [4 k-granule][1024 n] 16B granules (conflict-free, linear gload_lds).
// A chunk (tanh) reg-staged by waves 0-4 as [4 k-granule][80 m] granules.
// Wave = full 80M x 128N: 5x8 fragments of 16x16x32, acc 160 VGPR.
__global__ __launch_bounds__(512, 2) void k_joint(const float* __restrict__ encp,
                                                  const float* __restrict__ decp,
                                                  const unsigned short* __restrict__ wfc,
                                                  const float* __restrict__ bfc,
                                                  float* __restrict__ out) {
    __shared__ unsigned short Bs[2][4096 * 8];   // 128 KB
    __shared__ unsigned short As[2][320 * 8];    // 10 KB
    __shared__ float red[2][8][MB];              // 5 KB

    const int tid = threadIdx.x;
    const int wave = tid >> 6, lane = tid & 63;
    const int g = lane >> 4, ln = lane & 15;
    const int m0 = blockIdx.x * MB;

    // B gload source offsets (elements) for 8 rounds: granule G = r*512+tid -> (gk=G>>10, n=G&1023)
    int boff[8];
    #pragma unroll
    for (int r = 0; r < 8; ++r) {
        int G = r * 512 + tid;
        boff[r] = (G & 1023) * DJ + (G >> 10) * 8;
    }

    // A staging role: threads 0..319 (waves 0..4), one granule (gk, m) each
    const bool aRole = (tid < 320);
    const float *er = encp, *dr = decp;
    int agran = 0;
    if (aRole) {
        const int m = tid % MB;
        const int gk = tid / MB;
        const int mrow = m0 + m;
        const int b = mrow / (TT * UU);
        const int rem = mrow - b * (TT * UU);
        const int t = rem / UU;
        const int u = rem - t * UU;
        er = encp + (size_t)(b * TT + t) * DJ + gk * 8;
        dr = decp + (size_t)(b * UU + u) * DJ + gk * 8;
        agran = gk * MB + m;
    }

    f32x4 acc[5][8];
    #pragma unroll
    for (int mf = 0; mf < 5; ++mf)
        #pragma unroll
        for (int nf = 0; nf < 8; ++nf)
            acc[mf][nf] = (f32x4){0.f, 0.f, 0.f, 0.f};

    // ---- prologue: stage chunk 0 into buf 0 ----
    #pragma unroll
    for (int r = 0; r < 8; ++r)
        gload_lds16(wfc + boff[r], &Bs[0][(r * 512 + wave * 64) * 8]);
    if (aRole) {
        float4 e0 = *(const float4*)(er);
        float4 e1 = *(const float4*)(er + 4);
        float4 d0 = *(const float4*)(dr);
        float4 d1 = *(const float4*)(dr + 4);
        *(ushort8*)&As[0][agran * 8] = tanh_pack(e0, e1, d0, d1);
    }
    __syncthreads();

    // ---- main loop ----
    for (int it = 0; it < NITER; ++it) {
        const int cur = it & 1, nxt = cur ^ 1;
        const int k1 = (it + 1) * 32;
        float4 e0, e1, d0, d1;
        if (it < NITER - 1) {
            #pragma unroll
            for (int r = 0; r < 8; ++r)
                gload_lds16(wfc + boff[r] + k1, &Bs[nxt][(r * 512 + wave * 64) * 8]);
            if (aRole) {
                e0 = *(const float4*)(er + k1);
                e1 = *(const float4*)(er + k1 + 4);
                d0 = *(const float4*)(dr + k1);
                d1 = *(const float4*)(dr + k1 + 4);
            }
        }
        bf16x8 af[5];
        #pragma unroll
        for (int mf = 0; mf < 5; ++mf)
            af[mf] = *(const bf16x8*)&As[cur][(g * MB + mf * 16 + ln) * 8];
        #pragma unroll
        for (int nf = 0; nf < 8; ++nf) {
            bf16x8 bfr = *(const bf16x8*)&Bs[cur][(g * 1024 + wave * 128 + nf * 16 + ln) * 8];
            #pragma unroll
            for (int mf = 0; mf < 5; ++mf)
                acc[mf][nf] = __builtin_amdgcn_mfma_f32_16x16x32_bf16(af[mf], bfr, acc[mf][nf], 0, 0, 0);
        }
        if (it < NITER - 1 && aRole)
            *(ushort8*)&As[nxt][agran * 8] = tanh_pack(e0, e1, d0, d1);
        __syncthreads();
    }

    // ---- fused log_softmax epilogue ----
    // C frag (mf,nf): row = mf*16 + g*4 + j, col = wave*128 + nf*16 + ln
    float bv[8];
    #pragma unroll
    for (int nf = 0; nf < 8; ++nf) bv[nf] = bfc[wave * 128 + nf * 16 + ln];
    #pragma unroll
    for (int mf = 0; mf < 5; ++mf)
        #pragma unroll
        for (int nf = 0; nf < 8; ++nf)
            #pragma unroll
            for (int j = 0; j < 4; ++j)
                acc[mf][nf][j] += bv[nf];

    // row max (wave-local -> cross-wave)
    float rmx[5][4];
    #pragma unroll
    for (int mf = 0; mf < 5; ++mf)
        #pragma unroll
        for (int j = 0; j < 4; ++j) {
            float mx = -3.0e38f;
            #pragma unroll
            for (int nf = 0; nf < 8; ++nf) mx = fmaxf(mx, acc[mf][nf][j]);
            #pragma unroll
            for (int s = 1; s < 16; s <<= 1) mx = fmaxf(mx, __shfl_xor(mx, s));
            rmx[mf][j] = mx;
        }
    if (ln == 0) {
        #pragma unroll
        for (int mf = 0; mf < 5; ++mf)
            #pragma unroll
            for (int j = 0; j < 4; ++j)
                red[0][wave][mf * 16 + g * 4 + j] = rmx[mf][j];
    }
    __syncthreads();
    #pragma unroll
    for (int mf = 0; mf < 5; ++mf)
        #pragma unroll
        for (int j = 0; j < 4; ++j) {
            const int r = mf * 16 + g * 4 + j;
            float mx = red[0][0][r];
            #pragma unroll
            for (int w = 1; w < 8; ++w) mx = fmaxf(mx, red[0][w][r]);
            rmx[mf][j] = mx;
        }

    // sum of exp (wave-local -> cross-wave)
    float rsm[5][4];
    #pragma unroll
    for (int mf = 0; mf < 5; ++mf)
        #pragma unroll
        for (int j = 0; j < 4; ++j) {
            float s = 0.f;
            #pragma unroll
            for (int nf = 0; nf < 8; ++nf) s += __expf(acc[mf][nf][j] - rmx[mf][j]);
            #pragma unroll
            for (int t2 = 1; t2 < 16; t2 <<= 1) s += __shfl_xor(s, t2);
            rsm[mf][j] = s;
        }
    if (ln == 0) {
        #pragma unroll
        for (int mf = 0; mf < 5; ++mf)
            #pragma unroll
            for (int j = 0; j < 4; ++j)
                red[1][wave][mf * 16 + g * 4 + j] = rsm[mf][j];
    }
    __syncthreads();
    #pragma unroll
    for (int mf = 0; mf < 5; ++mf)
        #pragma unroll
        for (int j = 0; j < 4; ++j) {
            const int r = mf * 16 + g * 4 + j;
            float s = 0.f;
            #pragma unroll
            for (int w = 0; w < 8; ++w) s += red[1][w][r];
            const float lse = rmx[mf][j] + __logf(s);
            float* op = out + (size_t)(m0 + r) * VV + wave * 128 + ln;
            #pragma unroll
            for (int nf = 0; nf < 8; ++nf)
                op[nf * 16] = acc[mf][nf][j] - lse;
        }
}

extern "C" void kernel_launch(void* const* d_in, const int* in_sizes, int n_in,
                              void* d_out, int out_size, void* d_ws, size_t ws_size,
                              hipStream_t stream) {
    const float* enc   = (const float*)d_in[0];
    const float* dec   = (const float*)d_in[1];
    const float* W_enc = (const float*)d_in[2];
    const float* b_enc = (const float*)d_in[3];
    const float* W_dec = (const float*)d_in[4];
    const float* b_dec = (const float*)d_in[5];
    const float* W_fc  = (const float*)d_in[6];
    const float* b_fc  = (const float*)d_in[7];
    float* out = (float*)d_out;

    float* encp = (float*)d_ws;                              // 1600*1024 f32
    float* decp = encp + (size_t)BB * TT * DJ;               //  400*1024 f32
    unsigned short* wfcb = (unsigned short*)(decp + (size_t)BB * UU * DJ);  // 1024*1024 bf16

    k_wfc_bf16<<<(VV * DJ) / (256 * 8), 256, 0, stream>>>(W_fc, wfcb);
    k_proj<<<dim3((BB * TT) / 16, DJ / 256), 256, 0, stream>>>(enc, W_enc, b_enc, encp);
    k_proj<<<dim3((BB * UU) / 16, DJ / 256), 256, 0, stream>>>(dec, W_dec, b_dec, decp);
    k_joint<<<M_TOTAL / MB, 512, 0, stream>>>(encp, decp, wfcb, b_fc, out);
}

// Round 3
// 450.253 us; speedup vs baseline: 1.7505x; 1.7505x over previous
//
#include <hip/hip_runtime.h>
#include <hip/hip_bf16.h>

#define TT 200
#define UU 50
#define BB 8
#define DJ 1024   // D_JOINT
#define DE 512    // D_ENC / D_DEC
#define VV 1024
#define M_TOTAL (BB*TT*UU)   // 80000
#define MB 80                // M rows per block
#define NITER 32             // K / 32

typedef __bf16 bf16x8 __attribute__((ext_vector_type(8)));
typedef float f32x4 __attribute__((ext_vector_type(4)));
typedef unsigned short ushort8 __attribute__((ext_vector_type(8)));

__device__ __forceinline__ unsigned short f2bf(float f) {
    union { float f; unsigned u; } v; v.f = f;
    unsigned r = v.u + 0x7FFFu + ((v.u >> 16) & 1u);   // RNE
    return (unsigned short)(r >> 16);
}

__device__ __forceinline__ float fast_tanh(float x) {
    float e = __expf(2.f * x);
    return 1.f - 2.f / (e + 1.f);
}

__device__ __forceinline__ ushort8 tanh_pack(float4 e0, float4 e1, float4 d0, float4 d1) {
    ushort8 h;
    h[0] = f2bf(fast_tanh(e0.x + d0.x)); h[1] = f2bf(fast_tanh(e0.y + d0.y));
    h[2] = f2bf(fast_tanh(e0.z + d0.z)); h[3] = f2bf(fast_tanh(e0.w + d0.w));
    h[4] = f2bf(fast_tanh(e1.x + d1.x)); h[5] = f2bf(fast_tanh(e1.y + d1.y));
    h[6] = f2bf(fast_tanh(e1.z + d1.z)); h[7] = f2bf(fast_tanh(e1.w + d1.w));
    return h;
}

__device__ __forceinline__ void gload_lds16(const unsigned short* g, unsigned short* l) {
    __builtin_amdgcn_global_load_lds(
        (const __attribute__((address_space(1))) unsigned int*)(const void*)g,
        (__attribute__((address_space(3))) unsigned int*)(void*)l, 16, 0, 0);
}

// ---------- kernel 1: W_fc fp32 [n][k] -> bf16 granule-major [gk][n] ----------
// granule (n, gk) = W_fc[n][gk*8 .. gk*8+8) stored at o + (gk*1024+n)*8.
// Writes coalesced (consecutive G -> consecutive 16B); reads 32B scattered (L2/L3-absorbed, one-time).
__global__ void k_wfct(const float* __restrict__ w, unsigned short* __restrict__ o) {
    const int G = blockIdx.x * 256 + threadIdx.x;   // granule id, 131072 total
    const int gk = G >> 10, n = G & 1023;
    const float* src = w + (size_t)n * DJ + gk * 8;
    float4 a = *(const float4*)(src);
    float4 b = *(const float4*)(src + 4);
    ushort8 h;
    h[0] = f2bf(a.x); h[1] = f2bf(a.y); h[2] = f2bf(a.z); h[3] = f2bf(a.w);
    h[4] = f2bf(b.x); h[5] = f2bf(b.y); h[6] = f2bf(b.z); h[7] = f2bf(b.w);
    *(ushort8*)(o + (size_t)G * 8) = h;
}

// ---------- kernel 2: projection  out[m][j] = sum_d in[m][d]*W[j][d] + b[j] ----------
__global__ __launch_bounds__(256) void k_proj(const float* __restrict__ in,
                                              const float* __restrict__ W,
                                              const float* __restrict__ bias,
                                              float* __restrict__ out) {
    __shared__ float in_s[16][DE];
    const int m0 = blockIdx.x * 16;
    const int tid = threadIdx.x;
    #pragma unroll
    for (int it = 0; it < 8; ++it) {
        int idx = tid + it * 256;
        int r = idx >> 7, c = (idx & 127) << 2;
        *(float4*)&in_s[r][c] = *(const float4*)(in + (size_t)(m0 + r) * DE + c);
    }
    __syncthreads();
    const int j = blockIdx.y * 256 + tid;
    const float4* wr = (const float4*)(W + (size_t)j * DE);
    float acc[16];
    #pragma unroll
    for (int r = 0; r < 16; ++r) acc[r] = 0.f;
    for (int d4 = 0; d4 < DE / 4; ++d4) {
        float4 w = wr[d4];
        #pragma unroll
        for (int r = 0; r < 16; ++r) {
            float4 x = *(const float4*)&in_s[r][d4 << 2];
            acc[r] += x.x * w.x + x.y * w.y + x.z * w.z + x.w * w.w;
        }
    }
    float bv = bias[j];
    #pragma unroll
    for (int r = 0; r < 16; ++r)
        out[(size_t)(m0 + r) * DJ + j] = acc[r] + bv;
}

// ---------- kernel 3: fused tanh(enc+dec) @ W_fc^T + b_fc -> log_softmax ----------
// 512 threads (8 waves). Block tile: 80 M x 1024 N, K in 32-chunks, double-buffered.
// B: granule-major global (pre-transposed) -> each chunk is a CONTIGUOUS 64 KB region,
//    gload_lds fully coalesced, LDS layout [gk 0..3][n 0..1023] granules (2-way banks = free).
// A: tanh(enc+dec) reg-staged by threads 0..319 as [gk][m] granules, double-buffered.
// Wave = full 80M x 128N: 5x8 fragments of 16x16x32.
__global__ __launch_bounds__(512, 2) void k_joint(const float* __restrict__ encp,
                                                  const float* __restrict__ decp,
                                                  const unsigned short* __restrict__ wfcg,
                                                  const float* __restrict__ bfc,
                                                  float* __restrict__ out) {
    __shared__ unsigned short Bs[2][4096 * 8];   // 128 KB
    __shared__ unsigned short As[2][320 * 8];    // 10 KB
    __shared__ float red[8][MB];                 // 2.5 KB

    const int tid = threadIdx.x;
    const int wave = tid >> 6, lane = tid & 63;
    const int g = lane >> 4, ln = lane & 15;
    const int m0 = blockIdx.x * MB;

    // A staging role: threads 0..319 (waves 0..4), one granule (gk, m) each
    const bool aRole = (tid < 320);
    const float *er = encp, *dr = decp;
    int agran = 0;
    if (aRole) {
        const int m = tid % MB;
        const int gk = tid / MB;
        const int mrow = m0 + m;
        const int b = mrow / (TT * UU);
        const int rem = mrow - b * (TT * UU);
        const int t = rem / UU;
        const int u = rem - t * UU;
        er = encp + (size_t)(b * TT + t) * DJ + gk * 8;
        dr = decp + (size_t)(b * UU + u) * DJ + gk * 8;
        agran = gk * MB + m;
    }

    f32x4 acc[5][8];
    #pragma unroll
    for (int mf = 0; mf < 5; ++mf)
        #pragma unroll
        for (int nf = 0; nf < 8; ++nf)
            acc[mf][nf] = (f32x4){0.f, 0.f, 0.f, 0.f};

    // ---- prologue: stage chunk 0 into buf 0 (contiguous 64 KB, coalesced) ----
    #pragma unroll
    for (int r = 0; r < 8; ++r)
        gload_lds16(wfcg + (size_t)(r * 512 + tid) * 8, &Bs[0][(r * 512 + wave * 64) * 8]);
    if (aRole) {
        float4 e0 = *(const float4*)(er);
        float4 e1 = *(const float4*)(er + 4);
        float4 d0 = *(const float4*)(dr);
        float4 d1 = *(const float4*)(dr + 4);
        *(ushort8*)&As[0][agran * 8] = tanh_pack(e0, e1, d0, d1);
    }
    __syncthreads();

    // ---- main loop: 2-phase (issue next-chunk loads, then MFMA on current) ----
    for (int it = 0; it < NITER; ++it) {
        const int cur = it & 1, nxt = cur ^ 1;
        const int k1 = (it + 1) * 32;
        float4 e0, e1, d0, d1;
        if (it < NITER - 1) {
            const unsigned short* src = wfcg + (size_t)(it + 1) * 4096 * 8;
            #pragma unroll
            for (int r = 0; r < 8; ++r)
                gload_lds16(src + (size_t)(r * 512 + tid) * 8, &Bs[nxt][(r * 512 + wave * 64) * 8]);
            if (aRole) {
                e0 = *(const float4*)(er + k1);
                e1 = *(const float4*)(er + k1 + 4);
                d0 = *(const float4*)(dr + k1);
                d1 = *(const float4*)(dr + k1 + 4);
            }
        }
        bf16x8 af[5];
        #pragma unroll
        for (int mf = 0; mf < 5; ++mf)
            af[mf] = *(const bf16x8*)&As[cur][(g * MB + mf * 16 + ln) * 8];
        #pragma unroll
        for (int nf = 0; nf < 8; ++nf) {
            bf16x8 bfr = *(const bf16x8*)&Bs[cur][(g * 1024 + wave * 128 + nf * 16 + ln) * 8];
            #pragma unroll
            for (int mf = 0; mf < 5; ++mf)
                acc[mf][nf] = __builtin_amdgcn_mfma_f32_16x16x32_bf16(af[mf], bfr, acc[mf][nf], 0, 0, 0);
        }
        if (it < NITER - 1 && aRole)
            *(ushort8*)&As[nxt][agran * 8] = tanh_pack(e0, e1, d0, d1);
        __syncthreads();
    }

    // ---- fused log_softmax epilogue ----
    // C frag (mf,nf): row = mf*16 + g*4 + j, col = wave*128 + nf*16 + ln
    float bv[8];
    #pragma unroll
    for (int nf = 0; nf < 8; ++nf) bv[nf] = bfc[wave * 128 + nf * 16 + ln];
    #pragma unroll
    for (int mf = 0; mf < 5; ++mf)
        #pragma unroll
        for (int nf = 0; nf < 8; ++nf)
            #pragma unroll
            for (int j = 0; j < 4; ++j)
                acc[mf][nf][j] += bv[nf];

    // row max (wave-local -> cross-wave via red)
    float rmx[5][4];
    #pragma unroll
    for (int mf = 0; mf < 5; ++mf)
        #pragma unroll
        for (int j = 0; j < 4; ++j) {
            float mx = -3.0e38f;
            #pragma unroll
            for (int nf = 0; nf < 8; ++nf) mx = fmaxf(mx, acc[mf][nf][j]);
            #pragma unroll
            for (int s = 1; s < 16; s <<= 1) mx = fmaxf(mx, __shfl_xor(mx, s));
            rmx[mf][j] = mx;
        }
    if (ln == 0) {
        #pragma unroll
        for (int mf = 0; mf < 5; ++mf)
            #pragma unroll
            for (int j = 0; j < 4; ++j)
                red[wave][mf * 16 + g * 4 + j] = rmx[mf][j];
    }
    __syncthreads();
    #pragma unroll
    for (int mf = 0; mf < 5; ++mf)
        #pragma unroll
        for (int j = 0; j < 4; ++j) {
            const int r = mf * 16 + g * 4 + j;
            float mx = red[0][r];
            #pragma unroll
            for (int w = 1; w < 8; ++w) mx = fmaxf(mx, red[w][r]);
            rmx[mf][j] = mx;
        }
    __syncthreads();   // red reused for sums below

    // sum of exp (wave-local -> cross-wave)
    float rsm[5][4];
    #pragma unroll
    for (int mf = 0; mf < 5; ++mf)
        #pragma unroll
        for (int j = 0; j < 4; ++j) {
            float s = 0.f;
            #pragma unroll
            for (int nf = 0; nf < 8; ++nf) s += __expf(acc[mf][nf][j] - rmx[mf][j]);
            #pragma unroll
            for (int t2 = 1; t2 < 16; t2 <<= 1) s += __shfl_xor(s, t2);
            rsm[mf][j] = s;
        }
    if (ln == 0) {
        #pragma unroll
        for (int mf = 0; mf < 5; ++mf)
            #pragma unroll
            for (int j = 0; j < 4; ++j)
                red[wave][mf * 16 + g * 4 + j] = rsm[mf][j];
    }
    __syncthreads();
    #pragma unroll
    for (int mf = 0; mf < 5; ++mf)
        #pragma unroll
        for (int j = 0; j < 4; ++j) {
            const int r = mf * 16 + g * 4 + j;
            float s = 0.f;
            #pragma unroll
            for (int w = 0; w < 8; ++w) s += red[w][r];
            const float lse = rmx[mf][j] + __logf(s);
            float* op = out + (size_t)(m0 + r) * VV + wave * 128 + ln;
            #pragma unroll
            for (int nf = 0; nf < 8; ++nf)
                op[nf * 16] = acc[mf][nf][j] - lse;
        }
}

extern "C" void kernel_launch(void* const* d_in, const int* in_sizes, int n_in,
                              void* d_out, int out_size, void* d_ws, size_t ws_size,
                              hipStream_t stream) {
    const float* enc   = (const float*)d_in[0];
    const float* dec   = (const float*)d_in[1];
    const float* W_enc = (const float*)d_in[2];
    const float* b_enc = (const float*)d_in[3];
    const float* W_dec = (const float*)d_in[4];
    const float* b_dec = (const float*)d_in[5];
    const float* W_fc  = (const float*)d_in[6];
    const float* b_fc  = (const float*)d_in[7];
    float* out = (float*)d_out;

    float* encp = (float*)d_ws;                              // 1600*1024 f32
    float* decp = encp + (size_t)BB * TT * DJ;               //  400*1024 f32
    unsigned short* wfcg = (unsigned short*)(decp + (size_t)BB * UU * DJ);  // 2 MB bf16, granule-major

    k_wfct<<<(VV * DJ) / (256 * 8), 256, 0, stream>>>(W_fc, wfcg);
    k_proj<<<dim3((BB * TT) / 16, DJ / 256), 256, 0, stream>>>(enc, W_enc, b_enc, encp);
    k_proj<<<dim3((BB * UU) / 16, DJ / 256), 256, 0, stream>>>(dec, W_dec, b_dec, decp);
    k_joint<<<M_TOTAL / MB, 512, 0, stream>>>(encp, decp, wfcg, b_fc, out);
}